// Round 4
// baseline (139.969 us; speedup 1.0000x reference)
//
#include <hip/hip_runtime.h>
#include <hip/hip_bf16.h>

#define NTOK 128
#define CHN  512
#define KTOT 1024
#define EPSV 1e-5f

typedef __attribute__((ext_vector_type(8))) short bf16x8;
typedef __attribute__((ext_vector_type(4))) float f32x4;

union BfPack4 { ushort4 u; __hip_bfloat16 h[4]; };

// ---------------------------------------------------------------------------
// K1: block = (batch b, rows i0..i0+3), 256 threads (4 waves).
//  phase 0: Wf row blk -> bf16
//  phase 1: scores. LDS tile = packed float4 slots xs4[c4][j] with XOR swizzle
//           (j^c4) -> b128 writes AND reads, bank-balanced (8 lanes per 4-bank
//           cluster per wave op). Thread owns j-pair (j0, j0+64) and channel
//           quarter q (16 ch/round) -> xi/wd uniform loads amortize over 64 VALU.
//  softmax: shift-invariant (only BN scale + diagonal matter), uniform barriers
//  phase 2: xnb = W @ x[b], 2-way j-split, partials overlaid on xs tile
// ---------------------------------------------------------------------------
__global__ __launch_bounds__(256, 4)
void k1_score_softmax_xnb(const float* __restrict__ xg,
                          const float* __restrict__ wde,     // conv_e_w[:512]
                          const float* __restrict__ bn_e_g,
                          const float* __restrict__ bn_e_v,
                          const float* __restrict__ wf,      // conv_f_w [512][1024]
                          __hip_bfloat16* __restrict__ hb,   // [2048][1024]
                          __hip_bfloat16* __restrict__ wfb)  // [512][1024]
{
    __shared__ float4 xs4[16 * 128];     // 32 KB; overlays: part1 (8 KB) / part2 (16 KB)
    __shared__ float  wrow[4][128];      // softmax weights (live through phase 2)
    __shared__ float  red[16];
    float* pf = (float*)xs4;

    const int t   = threadIdx.x;
    const int blk = blockIdx.x;
    const int b   = blk >> 5;
    const int i0  = (blk & 31) << 2;
    const float* __restrict__ xb = xg + (size_t)b * NTOK * CHN;

    // ---- phase 0: Wf row blk -> bf16 (256 thr x 4 floats) ----
    {
        const float* wr = wf + (size_t)blk * KTOT;
        float4 u = *(const float4*)&wr[t * 4];
        BfPack4 p;
        p.h[0] = __float2bfloat16(u.x); p.h[1] = __float2bfloat16(u.y);
        p.h[2] = __float2bfloat16(u.z); p.h[3] = __float2bfloat16(u.w);
        *(ushort4*)&wfb[(size_t)blk * KTOT + t * 4] = p.u;
    }

    // ---- phase 1 ----
    const int j0 = t & 63;                                   // owned column pair (j0, j0+64)
    const int q  = __builtin_amdgcn_readfirstlane(t >> 6);   // channel quarter (wave-uniform)
    const int c4s = t & 15;          // staging: channel group within round
    const int jbs = t >> 4;          // staging: j base (0..15)

    float acc[4][2] = {{0.f,0.f},{0.f,0.f},{0.f,0.f},{0.f,0.f}};

    for (int s = 0; s < 8; ++s) {
        const int cs = s * 64;
        // stage x[b][all j][cs..cs+63] -> packed slots xs4[c4*128 + (j^c4)]
        #pragma unroll
        for (int u = 0; u < 8; ++u) {
            const int j = jbs + 16 * u;
            float4 v = *(const float4*)&xb[(size_t)j * CHN + cs + c4s * 4];
            xs4[c4s * 128 + (j ^ c4s)] = v;
        }
        __syncthreads();

        #pragma unroll
        for (int g = 0; g < 4; ++g) {
            const int c4r = q * 4 + g;
            const int c   = cs + c4r * 4;
            const int sl  = c4r * 128 + (j0 ^ c4r);          // (j0+64)^c4r = sl+64
            const float4 wd  = *(const float4*)&wde[c];                           // uniform
            const float4 xja = xs4[sl];
            const float4 xjb = xs4[sl + 64];
            #pragma unroll
            for (int r = 0; r < 4; ++r) {
                const float4 xi = *(const float4*)&xb[(size_t)(i0 + r) * CHN + c]; // uniform
                acc[r][0] += fabsf(xi.x - xja.x) * wd.x + fabsf(xi.y - xja.y) * wd.y
                           + fabsf(xi.z - xja.z) * wd.z + fabsf(xi.w - xja.w) * wd.w;
                acc[r][1] += fabsf(xi.x - xjb.x) * wd.x + fabsf(xi.y - xjb.y) * wd.y
                           + fabsf(xi.z - xjb.z) * wd.z + fabsf(xi.w - xjb.w) * wd.w;
            }
        }
        __syncthreads();
    }

    // ---- cross-quarter partials overlaid on xs tile: part1[q][r][j] ----
    #pragma unroll
    for (int r = 0; r < 4; ++r) {
        pf[q * 512 + r * 128 + j0]      = acc[r][0];
        pf[q * 512 + r * 128 + j0 + 64] = acc[r][1];
    }
    __syncthreads();

    // ---- softmax over j (threads 0..127 active; barriers uniform) ----
    const bool act = (t < 128);
    const int wid = t >> 6, lane = t & 63;
    float logit[4], pe[4];
    if (act) {
        const float sc = bn_e_g[0] * rsqrtf(bn_e_v[0] + EPSV);
        #pragma unroll
        for (int r = 0; r < 4; ++r) {
            logit[r] = (pf[0 * 512 + r * 128 + t] + pf[1 * 512 + r * 128 + t]
                      + pf[2 * 512 + r * 128 + t] + pf[3 * 512 + r * 128 + t]) * sc;
            if (t == i0 + r) logit[r] -= 1e8f;   // diagonal mask
        }
        #pragma unroll
        for (int r = 0; r < 4; ++r) {
            float v = logit[r];
            #pragma unroll
            for (int off = 32; off > 0; off >>= 1) v = fmaxf(v, __shfl_xor(v, off));
            if (lane == 0) red[wid * 8 + r] = v;
        }
    }
    __syncthreads();
    if (act) {
        #pragma unroll
        for (int r = 0; r < 4; ++r) {
            const float M = fmaxf(red[r], red[8 + r]);
            pe[r] = __expf(logit[r] - M);
            float v = pe[r];
            #pragma unroll
            for (int off = 32; off > 0; off >>= 1) v += __shfl_xor(v, off);
            if (lane == 0) red[wid * 8 + 4 + r] = v;
        }
    }
    __syncthreads();
    if (act) {
        #pragma unroll
        for (int r = 0; r < 4; ++r) {
            const float S = red[4 + r] + red[12 + r];
            wrow[r][t] = pe[r] / S;
        }
    }
    __syncthreads();   // wrow ready; xs tile free for part2 overlay

    // ---- phase 2: xnb = W @ x[b], 2-way j-split; partials into pf overlay ----
    const int jq  = __builtin_amdgcn_readfirstlane(t >> 7);
    const int c4f = (t & 127) * 4;
    float4 a2[4];
    #pragma unroll
    for (int r = 0; r < 4; ++r) { a2[r].x = a2[r].y = a2[r].z = a2[r].w = 0.f; }

    #pragma unroll 4
    for (int jj = 0; jj < 64; ++jj) {
        const int jx = jq * 64 + jj;
        const float4 xj = *(const float4*)&xb[(size_t)jx * CHN + c4f];
        const float w0 = wrow[0][jx], w1 = wrow[1][jx];
        const float w2 = wrow[2][jx], w3 = wrow[3][jx];
        a2[0].x += w0 * xj.x; a2[0].y += w0 * xj.y; a2[0].z += w0 * xj.z; a2[0].w += w0 * xj.w;
        a2[1].x += w1 * xj.x; a2[1].y += w1 * xj.y; a2[1].z += w1 * xj.z; a2[1].w += w1 * xj.w;
        a2[2].x += w2 * xj.x; a2[2].y += w2 * xj.y; a2[2].z += w2 * xj.z; a2[2].w += w2 * xj.w;
        a2[3].x += w3 * xj.x; a2[3].y += w3 * xj.y; a2[3].z += w3 * xj.z; a2[3].w += w3 * xj.w;
    }
    #pragma unroll
    for (int r = 0; r < 4; ++r)
        *(float4*)&pf[(jq * 4 + r) * CHN + c4f] = a2[r];
    __syncthreads();

    // ---- reduce + bf16 write of [x | xnb]; thread owns (row, 8 channels) ----
    {
        const int row = t >> 6;              // 0..3
        const int cc  = (t & 63) * 8;        // 0..504
        float4 p0a = *(const float4*)&pf[(0 + row) * CHN + cc];
        float4 p1a = *(const float4*)&pf[(4 + row) * CHN + cc];
        float4 p0b = *(const float4*)&pf[(0 + row) * CHN + cc + 4];
        float4 p1b = *(const float4*)&pf[(4 + row) * CHN + cc + 4];
        const size_t rowg = (size_t)(b * NTOK + i0 + row);
        BfPack4 pa, pb;
        pa.h[0] = __float2bfloat16(p0a.x + p1a.x);
        pa.h[1] = __float2bfloat16(p0a.y + p1a.y);
        pa.h[2] = __float2bfloat16(p0a.z + p1a.z);
        pa.h[3] = __float2bfloat16(p0a.w + p1a.w);
        pb.h[0] = __float2bfloat16(p0b.x + p1b.x);
        pb.h[1] = __float2bfloat16(p0b.y + p1b.y);
        pb.h[2] = __float2bfloat16(p0b.z + p1b.z);
        pb.h[3] = __float2bfloat16(p0b.w + p1b.w);
        *(ushort4*)&hb[rowg * KTOT + CHN + cc]     = pa.u;
        *(ushort4*)&hb[rowg * KTOT + CHN + cc + 4] = pb.u;

        const float4 xv0 = *(const float4*)&xb[(size_t)(i0 + row) * CHN + cc];
        const float4 xv1 = *(const float4*)&xb[(size_t)(i0 + row) * CHN + cc + 4];
        pa.h[0] = __float2bfloat16(xv0.x); pa.h[1] = __float2bfloat16(xv0.y);
        pa.h[2] = __float2bfloat16(xv0.z); pa.h[3] = __float2bfloat16(xv0.w);
        pb.h[0] = __float2bfloat16(xv1.x); pb.h[1] = __float2bfloat16(xv1.y);
        pb.h[2] = __float2bfloat16(xv1.z); pb.h[3] = __float2bfloat16(xv1.w);
        *(ushort4*)&hb[rowg * KTOT + cc]     = pa.u;
        *(ushort4*)&hb[rowg * KTOT + cc + 4] = pb.u;
    }
}

// ---------------------------------------------------------------------------
// K2: out = relu(BN([x|xnb] @ Wf^T + bias)) via bf16 MFMA, direct global frags.
// UNCHANGED (control).
// ---------------------------------------------------------------------------
__global__ __launch_bounds__(256)
void k2_gemm_bn_relu(const __hip_bfloat16* __restrict__ hbp,
                     const __hip_bfloat16* __restrict__ wfbp,
                     const float* __restrict__ fb,
                     const float* __restrict__ gg,
                     const float* __restrict__ bb,
                     const float* __restrict__ mm,
                     const float* __restrict__ vv,
                     float* __restrict__ out)
{
    const int blk  = blockIdx.x;
    const int r0   = (blk >> 3) << 6;
    const int c0   = (blk & 7) << 6;
    const int t    = threadIdx.x;
    const int w    = t >> 6;
    const int lane = t & 63;
    const int wm   = w & 1;
    const int wn   = w >> 1;
    const int m16  = lane & 15;
    const int qq   = lane >> 4;

    const short* A0 = (const short*)hbp  + (size_t)(r0 + wm * 32 + m16) * KTOT + qq * 8;
    const short* B0 = (const short*)wfbp + (size_t)(c0 + wn * 32 + m16) * KTOT + qq * 8;

    f32x4 acc00 = {0.f, 0.f, 0.f, 0.f};
    f32x4 acc01 = acc00, acc10 = acc00, acc11 = acc00;

    #pragma unroll 4
    for (int k0 = 0; k0 < KTOT; k0 += 32) {
        const bf16x8 aA = *(const bf16x8*)(A0 + k0);
        const bf16x8 aB = *(const bf16x8*)(A0 + 16 * KTOT + k0);
        const bf16x8 bA = *(const bf16x8*)(B0 + k0);
        const bf16x8 bB = *(const bf16x8*)(B0 + 16 * KTOT + k0);
        acc00 = __builtin_amdgcn_mfma_f32_16x16x32_bf16(aA, bA, acc00, 0, 0, 0);
        acc01 = __builtin_amdgcn_mfma_f32_16x16x32_bf16(aA, bB, acc01, 0, 0, 0);
        acc10 = __builtin_amdgcn_mfma_f32_16x16x32_bf16(aB, bA, acc10, 0, 0, 0);
        acc11 = __builtin_amdgcn_mfma_f32_16x16x32_bf16(aB, bB, acc11, 0, 0, 0);
    }

    // epilogue: C/D layout col = lane&15, row = (lane>>4)*4 + reg  [m89-verified]
    #pragma unroll
    for (int ni = 0; ni < 2; ++ni) {
        const int c = c0 + wn * 32 + ni * 16 + m16;
        const float gf = gg[c] * rsqrtf(vv[c] + EPSV);
        const float ad = fb[c] - mm[c];
        const float bv = bb[c];
        const f32x4 acr0 = ni ? acc01 : acc00;
        const f32x4 acr1 = ni ? acc11 : acc10;
        #pragma unroll
        for (int r2 = 0; r2 < 4; ++r2) {
            int row = r0 + wm * 32 + qq * 4 + r2;
            float val = (acr0[r2] + ad) * gf + bv;
            out[(size_t)row * CHN + c] = fmaxf(val, 0.f);
            row += 16;
            val = (acr1[r2] + ad) * gf + bv;
            out[(size_t)row * CHN + c] = fmaxf(val, 0.f);
        }
    }
}

extern "C" void kernel_launch(void* const* d_in, const int* in_sizes, int n_in,
                              void* d_out, int out_size, void* d_ws, size_t ws_size,
                              hipStream_t stream) {
    const float* x        = (const float*)d_in[0];
    // d_in[1] = y          : unused (softmax shift-invariance)
    const float* conv_e_w = (const float*)d_in[2];
    // d_in[3] = conv_e_b   : unused (shift)
    const float* bn_e_g   = (const float*)d_in[4];
    // d_in[5] = bn_e_b     : unused (shift)
    // d_in[6] = bn_e_m     : unused (shift)
    const float* bn_e_v   = (const float*)d_in[7];
    const float* conv_f_w = (const float*)d_in[8];
    const float* conv_f_b = (const float*)d_in[9];
    const float* bn_f_g   = (const float*)d_in[10];
    const float* bn_f_b   = (const float*)d_in[11];
    const float* bn_f_m   = (const float*)d_in[12];
    const float* bn_f_v   = (const float*)d_in[13];
    float* out = (float*)d_out;

    __hip_bfloat16* hb  = (__hip_bfloat16*)d_ws;              // 2048*1024 bf16 = 4 MB
    __hip_bfloat16* wfb = hb + (size_t)2048 * 1024;           // 512*1024 bf16  = 1 MB

    k1_score_softmax_xnb<<<512, 256, 0, stream>>>(x, conv_e_w, bn_e_g, bn_e_v,
                                                  conv_f_w, hb, wfb);
    k2_gemm_bn_relu<<<256, 256, 0, stream>>>(hb, wfb, conv_f_b, bn_f_g, bn_f_b,
                                             bn_f_m, bn_f_v, out);
}

// Round 5
// 123.314 us; speedup vs baseline: 1.1351x; 1.1351x over previous
//
#include <hip/hip_runtime.h>
#include <hip/hip_bf16.h>

#define NTOK 128
#define CHN  512
#define KTOT 1024
#define EPSV 1e-5f

typedef __attribute__((ext_vector_type(8))) short bf16x8;
typedef __attribute__((ext_vector_type(4))) float f32x4;

union BfPack4 { ushort4 u; __hip_bfloat16 h[4]; };

// ws layout (bytes):
//   0        : xT   fp32 [16][512][128]   4 MB
//   4  MB    : part fp32 [8][16][128][128] 8 MB
//   12 MB    : hb   bf16 [2048][1024]     4 MB
//   16 MB    : wfb  bf16 [512][1024]      1 MB
//   17 MB    : Wbf  bf16 [16][128][128]   512 KB
//   17.5 MB  : xTbf bf16 [16][512][128]   2 MB

// ---------------------------------------------------------------------------
// K0: per block (b, jt, ct): transpose a 64x64 tile of x into xT (fp32+bf16)
//     and emit bf16 x rows into hb-left. 256 blocks x 256 thr.
// ---------------------------------------------------------------------------
__global__ __launch_bounds__(256)
void k0_transpose(const float* __restrict__ xg,
                  float* __restrict__ xT,
                  __hip_bfloat16* __restrict__ xTbf,
                  __hip_bfloat16* __restrict__ hb)
{
    __shared__ float ts[64 * 68];   // pad 68: rows 16B-aligned
    const int t  = threadIdx.x;
    const int bk = blockIdx.x;
    const int b  = bk >> 4;
    const int jt = (bk >> 3) & 1;
    const int ct = bk & 7;
    const int j0 = jt * 64, c0 = ct * 64;

    // load 64 rows x 64 cols; thread: row j0+(t>>2), 16 floats at quad*16
    const int jr = t >> 2, qd = t & 3;
    const float* src = xg + ((size_t)(b * NTOK) + j0 + jr) * CHN + c0 + qd * 16;
    float4 v0 = *(const float4*)&src[0];
    float4 v1 = *(const float4*)&src[4];
    float4 v2 = *(const float4*)&src[8];
    float4 v3 = *(const float4*)&src[12];
    *(float4*)&ts[jr * 68 + qd * 16 + 0]  = v0;
    *(float4*)&ts[jr * 68 + qd * 16 + 4]  = v1;
    *(float4*)&ts[jr * 68 + qd * 16 + 8]  = v2;
    *(float4*)&ts[jr * 68 + qd * 16 + 12] = v3;

    // hb-left bf16 from registers (row b*128+j0+jr, cols c0+qd*16..+16)
    {
        __hip_bfloat16* hrow = hb + ((size_t)(b * NTOK) + j0 + jr) * KTOT + c0 + qd * 16;
        BfPack4 p;
        p.h[0]=__float2bfloat16(v0.x); p.h[1]=__float2bfloat16(v0.y);
        p.h[2]=__float2bfloat16(v0.z); p.h[3]=__float2bfloat16(v0.w);
        *(ushort4*)&hrow[0] = p.u;
        p.h[0]=__float2bfloat16(v1.x); p.h[1]=__float2bfloat16(v1.y);
        p.h[2]=__float2bfloat16(v1.z); p.h[3]=__float2bfloat16(v1.w);
        *(ushort4*)&hrow[4] = p.u;
        p.h[0]=__float2bfloat16(v2.x); p.h[1]=__float2bfloat16(v2.y);
        p.h[2]=__float2bfloat16(v2.z); p.h[3]=__float2bfloat16(v2.w);
        *(ushort4*)&hrow[8] = p.u;
        p.h[0]=__float2bfloat16(v3.x); p.h[1]=__float2bfloat16(v3.y);
        p.h[2]=__float2bfloat16(v3.z); p.h[3]=__float2bfloat16(v3.w);
        *(ushort4*)&hrow[12] = p.u;
    }
    __syncthreads();

    // write transposed: thread: cs = t>>4 (c = cs+16m), jj = (t&15)*4
    const int cs = t >> 4, jj = (t & 15) * 4;
    #pragma unroll
    for (int m = 0; m < 4; ++m) {
        const int c = cs + 16 * m;
        float4 o;
        o.x = ts[(jj + 0) * 68 + c];
        o.y = ts[(jj + 1) * 68 + c];
        o.z = ts[(jj + 2) * 68 + c];
        o.w = ts[(jj + 3) * 68 + c];
        const size_t base = ((size_t)(b * CHN) + c0 + c) * NTOK + j0 + jj;
        *(float4*)&xT[base] = o;
        BfPack4 p;
        p.h[0]=__float2bfloat16(o.x); p.h[1]=__float2bfloat16(o.y);
        p.h[2]=__float2bfloat16(o.z); p.h[3]=__float2bfloat16(o.w);
        *(ushort4*)&xTbf[base] = p.u;
    }
}

// ---------------------------------------------------------------------------
// K1a: partial scores. block = (b, i-quad, ch-slice of 64). 4096 blocks x 128
// thr, NO LDS, NO barriers. lane j reads xT coalesced; xi/wd wave-uniform.
// part[s][b][i][j] += sum_{c in slice} |x_i,c - x_j,c| * wd_c
// ---------------------------------------------------------------------------
__global__ __launch_bounds__(128)
void k1a_scores(const float* __restrict__ xg,
                const float* __restrict__ xT,
                const float* __restrict__ wde,
                float* __restrict__ part)
{
    const int bk = blockIdx.x;
    const int s  = bk & 7;
    const int iq = (bk >> 3) & 31;
    const int b  = bk >> 8;
    const int i0 = iq * 4;
    const int c0 = s * 64;
    const int j  = threadIdx.x;

    const float* xtp = xT + ((size_t)(b * CHN) + c0) * NTOK + j;
    const float* xip = xg + ((size_t)(b * NTOK) + i0) * CHN + c0;

    float acc0 = 0.f, acc1 = 0.f, acc2 = 0.f, acc3 = 0.f;

    #pragma unroll 2
    for (int cc = 0; cc < 64; cc += 8) {
        float xj[8];
        #pragma unroll
        for (int k = 0; k < 8; ++k) xj[k] = xtp[(cc + k) * NTOK];
        #pragma unroll
        for (int k = 0; k < 8; ++k) {
            const int c = cc + k;
            const float wd  = wde[c0 + c];          // uniform -> SGPR
            const float xi0 = xip[0 * CHN + c];     // uniform -> SGPR
            const float xi1 = xip[1 * CHN + c];
            const float xi2 = xip[2 * CHN + c];
            const float xi3 = xip[3 * CHN + c];
            acc0 += fabsf(xi0 - xj[k]) * wd;
            acc1 += fabsf(xi1 - xj[k]) * wd;
            acc2 += fabsf(xi2 - xj[k]) * wd;
            acc3 += fabsf(xi3 - xj[k]) * wd;
        }
    }

    float* pp = part + ((size_t)s * 16 + b) * (NTOK * NTOK) + (size_t)i0 * NTOK + j;
    pp[0 * NTOK] = acc0;
    pp[1 * NTOK] = acc1;
    pp[2 * NTOK] = acc2;
    pp[3 * NTOK] = acc3;
}

// ---------------------------------------------------------------------------
// K1b: softmax per row. 1024 blocks x 128 thr; wave w owns row i0+w.
// lane l handles j=l and j=l+64. Butterfly-only, no LDS, no barriers.
// Writes W as bf16 (rows k=j contiguous, ready as MFMA A-operand source).
// ---------------------------------------------------------------------------
__global__ __launch_bounds__(128)
void k1b_softmax(const float* __restrict__ part,
                 const float* __restrict__ bn_e_g,
                 const float* __restrict__ bn_e_v,
                 __hip_bfloat16* __restrict__ Wbf)
{
    const int bk = blockIdx.x;
    const int b  = bk >> 6;
    const int i  = (bk & 63) * 2 + (threadIdx.x >> 6);
    const int l  = threadIdx.x & 63;

    const float* pp = part + (size_t)(b * NTOK + i) * NTOK;
    float p1 = 0.f, p2 = 0.f;
    #pragma unroll
    for (int s = 0; s < 8; ++s) {
        p1 += pp[(size_t)s * 16 * NTOK * NTOK + l];
        p2 += pp[(size_t)s * 16 * NTOK * NTOK + l + 64];
    }
    const float sc = bn_e_g[0] * rsqrtf(bn_e_v[0] + EPSV);
    float l1 = p1 * sc - (l == i ? 1e8f : 0.f);
    float l2 = p2 * sc - (l + 64 == i ? 1e8f : 0.f);

    float m = fmaxf(l1, l2);
    #pragma unroll
    for (int off = 32; off > 0; off >>= 1) m = fmaxf(m, __shfl_xor(m, off));
    const float e1 = __expf(l1 - m);
    const float e2 = __expf(l2 - m);
    float ssum = e1 + e2;
    #pragma unroll
    for (int off = 32; off > 0; off >>= 1) ssum += __shfl_xor(ssum, off);
    const float inv = 1.f / ssum;

    __hip_bfloat16* wr = Wbf + (size_t)(b * NTOK + i) * NTOK;
    wr[l]      = __float2bfloat16(e1 * inv);
    wr[l + 64] = __float2bfloat16(e2 * inv);
}

// ---------------------------------------------------------------------------
// K1c: xnb = W @ x via bf16 MFMA -> hb right half; also converts Wf -> bf16.
// 512 blocks x 256 thr. Block: (b, i-tile 32, c-tile 64), K = 128 (j).
// ---------------------------------------------------------------------------
__global__ __launch_bounds__(256)
void k1c_xnb(const __hip_bfloat16* __restrict__ Wbf,
             const __hip_bfloat16* __restrict__ xTbf,
             const float* __restrict__ wf,
             __hip_bfloat16* __restrict__ hb,
             __hip_bfloat16* __restrict__ wfb)
{
    const int bk = blockIdx.x;
    const int t  = threadIdx.x;

    // Wf row bk -> bf16 (independent of the GEMM below)
    {
        const float* wr = wf + (size_t)bk * KTOT;
        float4 u = *(const float4*)&wr[t * 4];
        BfPack4 p;
        p.h[0]=__float2bfloat16(u.x); p.h[1]=__float2bfloat16(u.y);
        p.h[2]=__float2bfloat16(u.z); p.h[3]=__float2bfloat16(u.w);
        *(ushort4*)&wfb[(size_t)bk * KTOT + t * 4] = p.u;
    }

    const int b  = bk >> 5;
    const int mt = (bk >> 3) & 3;     // i-tile of 32
    const int ct = bk & 7;            // c-tile of 64
    const int i0 = mt * 32, c0 = ct * 64;

    const int w    = t >> 6;
    const int lane = t & 63;
    const int wm   = w & 1;           // 16-row half
    const int wn   = w >> 1;          // 32-col half
    const int m16  = lane & 15;
    const int q    = lane >> 4;

    const short* A0 = (const short*)Wbf  + (size_t)(b * NTOK + i0 + wm * 16 + m16) * NTOK + q * 8;
    const short* B0 = (const short*)xTbf + ((size_t)(b * CHN) + c0 + wn * 32 + m16) * NTOK + q * 8;

    f32x4 acc0 = {0.f, 0.f, 0.f, 0.f};
    f32x4 acc1 = acc0;

    #pragma unroll
    for (int k0 = 0; k0 < NTOK; k0 += 32) {
        const bf16x8 a  = *(const bf16x8*)(A0 + k0);
        const bf16x8 b0 = *(const bf16x8*)(B0 + k0);
        const bf16x8 b1 = *(const bf16x8*)(B0 + 16 * NTOK + k0);
        acc0 = __builtin_amdgcn_mfma_f32_16x16x32_bf16(a, b0, acc0, 0, 0, 0);
        acc1 = __builtin_amdgcn_mfma_f32_16x16x32_bf16(a, b1, acc1, 0, 0, 0);
    }

    // D layout: col = lane&15 (-> c), row = q*4+r (-> i)  [verified pattern]
    #pragma unroll
    for (int ni = 0; ni < 2; ++ni) {
        const int c = c0 + wn * 32 + ni * 16 + m16;
        const f32x4 ac = ni ? acc1 : acc0;
        #pragma unroll
        for (int r = 0; r < 4; ++r) {
            const int i = i0 + wm * 16 + q * 4 + r;
            hb[(size_t)(b * NTOK + i) * KTOT + CHN + c] = __float2bfloat16(ac[r]);
        }
    }
}

// ---------------------------------------------------------------------------
// K2: out = relu(BN([x|xnb] @ Wf^T + bias)) via bf16 MFMA. UNCHANGED (control).
// ---------------------------------------------------------------------------
__global__ __launch_bounds__(256)
void k2_gemm_bn_relu(const __hip_bfloat16* __restrict__ hbp,
                     const __hip_bfloat16* __restrict__ wfbp,
                     const float* __restrict__ fb,
                     const float* __restrict__ gg,
                     const float* __restrict__ bb,
                     const float* __restrict__ mm,
                     const float* __restrict__ vv,
                     float* __restrict__ out)
{
    const int blk  = blockIdx.x;
    const int r0   = (blk >> 3) << 6;
    const int c0   = (blk & 7) << 6;
    const int t    = threadIdx.x;
    const int w    = t >> 6;
    const int lane = t & 63;
    const int wm   = w & 1;
    const int wn   = w >> 1;
    const int m16  = lane & 15;
    const int qq   = lane >> 4;

    const short* A0 = (const short*)hbp  + (size_t)(r0 + wm * 32 + m16) * KTOT + qq * 8;
    const short* B0 = (const short*)wfbp + (size_t)(c0 + wn * 32 + m16) * KTOT + qq * 8;

    f32x4 acc00 = {0.f, 0.f, 0.f, 0.f};
    f32x4 acc01 = acc00, acc10 = acc00, acc11 = acc00;

    #pragma unroll 4
    for (int k0 = 0; k0 < KTOT; k0 += 32) {
        const bf16x8 aA = *(const bf16x8*)(A0 + k0);
        const bf16x8 aB = *(const bf16x8*)(A0 + 16 * KTOT + k0);
        const bf16x8 bA = *(const bf16x8*)(B0 + k0);
        const bf16x8 bB = *(const bf16x8*)(B0 + 16 * KTOT + k0);
        acc00 = __builtin_amdgcn_mfma_f32_16x16x32_bf16(aA, bA, acc00, 0, 0, 0);
        acc01 = __builtin_amdgcn_mfma_f32_16x16x32_bf16(aA, bB, acc01, 0, 0, 0);
        acc10 = __builtin_amdgcn_mfma_f32_16x16x32_bf16(aB, bA, acc10, 0, 0, 0);
        acc11 = __builtin_amdgcn_mfma_f32_16x16x32_bf16(aB, bB, acc11, 0, 0, 0);
    }

    #pragma unroll
    for (int ni = 0; ni < 2; ++ni) {
        const int c = c0 + wn * 32 + ni * 16 + m16;
        const float gf = gg[c] * rsqrtf(vv[c] + EPSV);
        const float ad = fb[c] - mm[c];
        const float bv = bb[c];
        const f32x4 acr0 = ni ? acc01 : acc00;
        const f32x4 acr1 = ni ? acc11 : acc10;
        #pragma unroll
        for (int r2 = 0; r2 < 4; ++r2) {
            int row = r0 + wm * 32 + qq * 4 + r2;
            float val = (acr0[r2] + ad) * gf + bv;
            out[(size_t)row * CHN + c] = fmaxf(val, 0.f);
            row += 16;
            val = (acr1[r2] + ad) * gf + bv;
            out[(size_t)row * CHN + c] = fmaxf(val, 0.f);
        }
    }
}

extern "C" void kernel_launch(void* const* d_in, const int* in_sizes, int n_in,
                              void* d_out, int out_size, void* d_ws, size_t ws_size,
                              hipStream_t stream) {
    const float* x        = (const float*)d_in[0];
    // d_in[1] = y          : unused (softmax shift-invariance)
    const float* conv_e_w = (const float*)d_in[2];
    // d_in[3] = conv_e_b   : unused (shift)
    const float* bn_e_g   = (const float*)d_in[4];
    // d_in[5,6] bn_e_b, bn_e_m : unused (shift)
    const float* bn_e_v   = (const float*)d_in[7];
    const float* conv_f_w = (const float*)d_in[8];
    const float* conv_f_b = (const float*)d_in[9];
    const float* bn_f_g   = (const float*)d_in[10];
    const float* bn_f_b   = (const float*)d_in[11];
    const float* bn_f_m   = (const float*)d_in[12];
    const float* bn_f_v   = (const float*)d_in[13];
    float* out = (float*)d_out;

    char* ws = (char*)d_ws;
    float*           xT   = (float*)(ws);                               // 4 MB
    float*           part = (float*)(ws + (4u << 20));                  // 8 MB
    __hip_bfloat16*  hb   = (__hip_bfloat16*)(ws + (12u << 20));        // 4 MB
    __hip_bfloat16*  wfb  = (__hip_bfloat16*)(ws + (16u << 20));        // 1 MB
    __hip_bfloat16*  Wbf  = (__hip_bfloat16*)(ws + (17u << 20));        // 512 KB
    __hip_bfloat16*  xTbf = (__hip_bfloat16*)(ws + (17u << 20) + (512u << 10)); // 2 MB

    k0_transpose<<<256, 256, 0, stream>>>(x, xT, xTbf, hb);
    k1a_scores<<<4096, 128, 0, stream>>>(x, xT, conv_e_w, part);
    k1b_softmax<<<1024, 128, 0, stream>>>(part, bn_e_g, bn_e_v, Wbf);
    k1c_xnb<<<512, 256, 0, stream>>>(Wbf, xTbf, conv_f_w, hb, wfb);
    k2_gemm_bn_relu<<<256, 256, 0, stream>>>(hb, wfb, conv_f_b, bn_f_g, bn_f_b,
                                             bn_f_m, bn_f_v, out);
}